// Round 2
// baseline (333.703 us; speedup 1.0000x reference)
//
#include <hip/hip_runtime.h>
#include <math.h>

// 19-qubit statevector sim, single persistent kernel.
// Wire w <-> global bit (18-w). State: flat 2^19 float2 in d_ws.
// Per edge-pass i, active qubits: edge i (bit 18-i), neighbor (bit 9-i),
// anc1 (bit 1), anc2 (bit 0). Each thread owns the 16-amp subspace of those
// 4 qubits for one 15-bit spectator combo -> whole pass in registers.
// Grid barriers (device-scope atomics) between passes. Final stage: update
// block on {center(bit10), anc1, anc2} + H + signed-prob reduction.

#define GRID 128
#define TPB  256

struct cplx { float x, y; };
__device__ __forceinline__ cplx cmul(cplx a, cplx b){ return {a.x*b.x - a.y*b.y, a.x*b.y + a.y*b.x}; }
__device__ __forceinline__ cplx cadd(cplx a, cplx b){ return {a.x+b.x, a.y+b.y}; }

__device__ __forceinline__ void mat2mul(const cplx* A, const cplx* B, cplx* C){
  C[0] = cadd(cmul(A[0],B[0]), cmul(A[1],B[2]));
  C[1] = cadd(cmul(A[0],B[1]), cmul(A[1],B[3]));
  C[2] = cadd(cmul(A[2],B[0]), cmul(A[3],B[2]));
  C[3] = cadd(cmul(A[2],B[1]), cmul(A[3],B[3]));
}
__device__ void mk_rz(float t, cplx* M){ float s,c; sincosf(0.5f*t,&s,&c); M[0]={c,-s};M[1]={0,0};M[2]={0,0};M[3]={c,s}; }
__device__ void mk_ry(float t, cplx* M){ float s,c; sincosf(0.5f*t,&s,&c); M[0]={c,0};M[1]={-s,0};M[2]={s,0};M[3]={c,0}; }
__device__ void mk_rx(float t, cplx* M){ float s,c; sincosf(0.5f*t,&s,&c); M[0]={c,0};M[1]={0,-s};M[2]={0,-s};M[3]={c,0}; }
// Rx(p2) Ry(p1) Rz(p0)
__device__ void mk_strong(const float* p, cplx* M){
  cplx Rz[4],Ry[4],Rx[4],T[4];
  mk_rz(p[0],Rz); mk_ry(p[1],Ry); mk_rx(p[2],Rx);
  mat2mul(Ry,Rz,T); mat2mul(Rx,T,M);
}
// Rz(tz) Ry(ty)
__device__ void mk_ryrz(float ty, float tz, cplx* M){
  cplx Rz[4],Ry[4]; mk_rz(tz,Rz); mk_ry(ty,Ry); mat2mul(Rz,Ry,M);
}

// apply 2x2 M on bit-stride S; if C!=0 only where cond bit set
template<int N, int S, int C>
__device__ __forceinline__ void rotg(cplx* r, const cplx* M){
  #pragma unroll
  for (int j = 0; j < N; ++j){
    if (j & S) continue;
    if (C && !(j & C)) continue;
    cplx a = r[j], b = r[j | S];
    r[j]     = cadd(cmul(M[0], a), cmul(M[1], b));
    r[j | S] = cadd(cmul(M[2], a), cmul(M[3], b));
  }
}
template<int N, int S, int C>
__device__ __forceinline__ void cnotg(cplx* r){
  #pragma unroll
  for (int j = 0; j < N; ++j){
    if (j & S) continue;
    if (!(j & C)) continue;
    cplx t = r[j]; r[j] = r[j | S]; r[j | S] = t;
  }
}

__device__ __forceinline__ int insert0(int x, int b){
  return ((x >> b) << (b + 1)) | (x & ((1 << b) - 1));
}

__device__ __forceinline__ void ld4(const float2* st, int a, cplx* r){
  const float4* p = reinterpret_cast<const float4*>(st + a);
  float4 u = p[0], v = p[1];
  r[0] = {u.x, u.y}; r[1] = {u.z, u.w}; r[2] = {v.x, v.y}; r[3] = {v.z, v.w};
}
__device__ __forceinline__ void st4(float2* st, int a, const cplx* r){
  float4* p = reinterpret_cast<float4*>(st + a);
  p[0] = make_float4(r[0].x, r[0].y, r[1].x, r[1].y);
  p[1] = make_float4(r[2].x, r[2].y, r[3].x, r[3].y);
}

__device__ __forceinline__ void gridbar(int* bar, int gen){
  __threadfence();
  __syncthreads();
  if (threadIdx.x == 0){
    __hip_atomic_fetch_add(bar, 1, __ATOMIC_RELEASE, __HIP_MEMORY_SCOPE_AGENT);
    while (__hip_atomic_load(bar, __ATOMIC_ACQUIRE, __HIP_MEMORY_SCOPE_AGENT) < gen * GRID)
      __builtin_amdgcn_s_sleep(2);
  }
  __syncthreads();
  __threadfence();
}

__global__ __launch_bounds__(TPB)
void qsim(const float* __restrict__ inf, const float* __restrict__ inits,
          const float* __restrict__ s0p, const float* __restrict__ s1p,
          const float* __restrict__ up, float* __restrict__ out,
          float2* __restrict__ st, int* __restrict__ bar, float* __restrict__ accum)
{
  const int T = blockIdx.x * TPB + threadIdx.x;   // 0..32767
  __shared__ float wsum[TPB / 64];

  // pass-invariant gate matrices (uniform across threads)
  cplx Mcrx[4], Mcry1[4], Mcrz[4], Mcry2[4];
  mk_rx(inits[0], Mcrx); mk_ry(inits[1], Mcry1);
  mk_rz(inits[2], Mcrz); mk_ry(inits[3], Mcry2);
  cplx S0e[4], S0n[4], S0a[4], S1a[4], S1n[4], S1x[4];
  mk_strong(s0p + 0, S0e); mk_strong(s0p + 3, S0n); mk_strong(s0p + 6, S0a);
  mk_strong(s1p + 0, S1a); mk_strong(s1p + 3, S1n); mk_strong(s1p + 6, S1x);

  int gen = 0;
  for (int i = 0; i < 8; ++i){
    cplx Ue[4]; mk_ryrz(inf[2*i], inf[2*i + 1], Ue);
    const int nb = 9 - i, eb = 18 - i;
    const int base = insert0(insert0(T << 2, nb), eb);
    const int zmask = ((1 << (7 - i)) - 1) << 11;   // edges i+1..7 must be 0
    const bool active = (base & zmask) == 0;
    cplx r[16];
    if (i == 0){
      #pragma unroll
      for (int j = 0; j < 16; ++j) r[j] = {0.f, 0.f};
      if (active){
        // initial product state: verts rotated (bits 10..2), rest |0>
        cplx amp = {1.f, 0.f}; cplx vn0 = {0,0}, vn1 = {0,0};
        #pragma unroll
        for (int v = 0; v < 9; ++v){
          float sy, cy, sz, cz;
          sincosf(0.5f * inf[16 + 2*v], &sy, &cy);
          sincosf(0.5f * inf[17 + 2*v], &sz, &cz);
          cplx q0 = {cy*cz, -cy*sz}, q1 = {sy*cz, sy*sz};
          if (v == 1){ vn0 = q0; vn1 = q1; }                 // neighbor of pass 0
          else amp = cmul(amp, ((base >> (10 - v)) & 1) ? q1 : q0);
        }
        r[0] = cmul(amp, vn0);   // e=0,n=0,a1=0,a2=0
        r[4] = cmul(amp, vn1);   // e=0,n=1
      }
    } else if (active){
      ld4(st, base,             r + 0);        // e=0, n=0
      ld4(st, base | (1 << nb), r + 4);        // e=0, n=1
      #pragma unroll
      for (int j = 8; j < 16; ++j) r[j] = {0.f, 0.f};  // edge i still |0>
    }
    if (active){
      // index j = e*8 + n*4 + a1*2 + a2
      rotg<16, 8, 0>(r, Ue);                    // Rz*Ry init on edge i
      rotg<16, 2, 4>(r, Mcrx);                  // CRx(neighbor -> anc1)
      rotg<16, 2, 8>(r, Mcry1);                 // CRy(edge -> anc1)
      rotg<16, 1, 4>(r, Mcrz);                  // CRz(neighbor -> anc2)
      rotg<16, 1, 8>(r, Mcry2);                 // CRy(edge -> anc2)
      rotg<16, 8, 0>(r, S0e);                   // strong0 rotations
      rotg<16, 4, 0>(r, S0n);
      rotg<16, 2, 0>(r, S0a);
      cnotg<16, 4, 8>(r);                       // CNOT(edge -> neighbor)
      cnotg<16, 2, 4>(r);                       // CNOT(neighbor -> anc1)
      cnotg<16, 8, 2>(r);                       // CNOT(anc1 -> edge)
      rotg<16, 2, 0>(r, S1a);                   // strong1 rotations
      rotg<16, 4, 0>(r, S1n);
      rotg<16, 1, 0>(r, S1x);
      cnotg<16, 4, 2>(r);                       // CNOT(anc1 -> neighbor)
      cnotg<16, 1, 4>(r);                       // CNOT(neighbor -> anc2)
      cnotg<16, 2, 1>(r);                       // CNOT(anc2 -> anc1)
    }
    if (active || i == 0){                      // pass 0 zero-fills whole buffer
      st4(st, base,                         r + 0);
      st4(st, base | (1 << nb),             r + 4);
      st4(st, base | (1 << eb),             r + 8);
      st4(st, base | (1 << eb) | (1 << nb), r + 12);
    }
    gridbar(bar, ++gen);
  }

  // final: update strong block on {center(bit10), anc1(bit1), anc2(bit0)},
  // H on center, measure Z on global bit 8 (reference's axis quirk).
  cplx Uc[4], Ua1[4], Ua2[4];
  mk_strong(up + 0, Uc); mk_strong(up + 3, Ua1); mk_strong(up + 6, Ua2);
  const float rh = 0.70710678118654752f;
  cplx HH[4] = {{rh,0.f},{rh,0.f},{rh,0.f},{-rh,0.f}};
  float s = 0.f;
  #pragma unroll
  for (int u = 0; u < 2; ++u){
    const int C = T + u * 32768;                       // 16 spectator bits
    const int base = ((C & 0xFF) << 2) | ((C >> 8) << 11);
    cplx r[8];                                         // j = c*4 + a1*2 + a2
    ld4(st, base,        r + 0);
    ld4(st, base | 1024, r + 4);
    rotg<8, 4, 0>(r, Uc);
    rotg<8, 2, 0>(r, Ua1);
    rotg<8, 1, 0>(r, Ua2);
    cnotg<8, 2, 4>(r);                                 // CNOT(center -> anc1)
    cnotg<8, 1, 2>(r);                                 // CNOT(anc1 -> anc2)
    cnotg<8, 4, 1>(r);                                 // CNOT(anc2 -> center)
    rotg<8, 4, 0>(r, HH);                              // H on center
    float p = 0.f;
    #pragma unroll
    for (int j = 0; j < 8; ++j) p += r[j].x*r[j].x + r[j].y*r[j].y;
    s += ((base >> 8) & 1) ? -p : p;
  }
  for (int off = 32; off > 0; off >>= 1) s += __shfl_down(s, off);
  if ((threadIdx.x & 63) == 0) wsum[threadIdx.x >> 6] = s;
  __syncthreads();
  if (threadIdx.x == 0) atomicAdd(accum, wsum[0] + wsum[1] + wsum[2] + wsum[3]);
  gridbar(bar, ++gen);
  if (blockIdx.x == 0 && threadIdx.x == 0)
    out[0] = __hip_atomic_load(accum, __ATOMIC_RELAXED, __HIP_MEMORY_SCOPE_AGENT);
}

extern "C" void kernel_launch(void* const* d_in, const int* in_sizes, int n_in,
                              void* d_out, int out_size, void* d_ws, size_t ws_size,
                              hipStream_t stream) {
  const float* inf   = (const float*)d_in[0];
  const float* inits = (const float*)d_in[1];
  const float* s0p   = (const float*)d_in[2];
  const float* s1p   = (const float*)d_in[3];
  const float* up    = (const float*)d_in[4];
  float* out = (float*)d_out;

  float2* st   = (float2*)d_ws;                         // 2^19 * 8 B = 4 MiB
  char*  ctrl  = (char*)d_ws + (1 << 22);
  int*   bar   = (int*)ctrl;
  float* accum = (float*)(ctrl + 64);

  hipMemsetAsync(ctrl, 0, 128, stream);                 // zero barrier + accum
  qsim<<<dim3(GRID), dim3(TPB), 0, stream>>>(inf, inits, s0p, s1p, up, out, st, bar, accum);
}

// Round 3
// 115.675 us; speedup vs baseline: 2.8848x; 2.8848x over previous
//
#include <hip/hip_runtime.h>
#include <math.h>

// 19-qubit statevector sim in TWO kernels (global sync = kernel boundary).
// Wire w <-> global bit g(18-w).
// Passes 0-3 active bits: {g18..g15 (edges), g9..g6 (neighbors), g1 (anc1), g0 (anc2)}
// Passes 4-7 + finale:    {g14..g11, g5..g2, g10 (center), g1, g0}
// segA: 8 blocks x 256, 12 local bits {g0,g1,g2,g6..g10,g15..g18}, block bits {g3,g4,g5}.
//       Support has g11..g14 == 0 throughout (edges 4..7 untouched) -> 2^15 amps.
// segB: 128 blocks x 256, 12 local bits {g0..g6,g10,g11..g14}, block bits {g7,g8,g9,g15..g18}.
// Interface: packed 15-bit support index s = [g18..g15 | g10..g0] in d_ws (256 KB).
// Within a pass each thread owns an exclusive 16-amp group (4 active bits) in
// registers; regroup via LDS with one __syncthreads between passes.

struct cplx { float x, y; };
__device__ __forceinline__ cplx cmul(cplx a, cplx b){ return {a.x*b.x - a.y*b.y, a.x*b.y + a.y*b.x}; }
__device__ __forceinline__ cplx cadd(cplx a, cplx b){ return {a.x+b.x, a.y+b.y}; }

__device__ __forceinline__ void mat2mul(const cplx* A, const cplx* B, cplx* C){
  C[0] = cadd(cmul(A[0],B[0]), cmul(A[1],B[2]));
  C[1] = cadd(cmul(A[0],B[1]), cmul(A[1],B[3]));
  C[2] = cadd(cmul(A[2],B[0]), cmul(A[3],B[2]));
  C[3] = cadd(cmul(A[2],B[1]), cmul(A[3],B[3]));
}
__device__ void mk_rz(float t, cplx* M){ float s,c; sincosf(0.5f*t,&s,&c); M[0]={c,-s};M[1]={0,0};M[2]={0,0};M[3]={c,s}; }
__device__ void mk_ry(float t, cplx* M){ float s,c; sincosf(0.5f*t,&s,&c); M[0]={c,0};M[1]={-s,0};M[2]={s,0};M[3]={c,0}; }
__device__ void mk_rx(float t, cplx* M){ float s,c; sincosf(0.5f*t,&s,&c); M[0]={c,0};M[1]={0,-s};M[2]={0,-s};M[3]={c,0}; }
// Rx(p2) Ry(p1) Rz(p0)
__device__ void mk_strong(const float* p, cplx* M){
  cplx Rz[4],Ry[4],Rx[4],T[4];
  mk_rz(p[0],Rz); mk_ry(p[1],Ry); mk_rx(p[2],Rx);
  mat2mul(Ry,Rz,T); mat2mul(Rx,T,M);
}
// Rz(tz) Ry(ty)
__device__ void mk_ryrz(float ty, float tz, cplx* M){
  cplx Rz[4],Ry[4]; mk_rz(tz,Rz); mk_ry(ty,Ry); mat2mul(Rz,Ry,M);
}

template<int N, int S, int C>
__device__ __forceinline__ void rotg(cplx* r, const cplx* M){
  #pragma unroll
  for (int j = 0; j < N; ++j){
    if (j & S) continue;
    if (C && !(j & C)) continue;
    cplx a = r[j], b = r[j | S];
    r[j]     = cadd(cmul(M[0], a), cmul(M[1], b));
    r[j | S] = cadd(cmul(M[2], a), cmul(M[3], b));
  }
}
template<int N, int S, int C>
__device__ __forceinline__ void cnotg(cplx* r){
  #pragma unroll
  for (int j = 0; j < N; ++j){
    if (j & S) continue;
    if (!(j & C)) continue;
    cplx t = r[j]; r[j] = r[j | S]; r[j | S] = t;
  }
}

__device__ __forceinline__ int ins0(int x, int b){
  return ((x >> b) << (b + 1)) | (x & ((1 << b) - 1));
}

// full edge-iteration gate sequence; j = (e<<3)|(n<<2)|(a1<<1)|a2
__device__ __forceinline__ void edge_pass(cplx* r, const cplx* Ue,
    const cplx* Mcrx, const cplx* Mcry1, const cplx* Mcrz, const cplx* Mcry2,
    const cplx* S0e, const cplx* S0n, const cplx* S0a,
    const cplx* S1a, const cplx* S1n, const cplx* S1x)
{
  rotg<16,8,0>(r, Ue);      // RzRy init on edge
  rotg<16,2,4>(r, Mcrx);    // CRx(neighbor -> anc1)
  rotg<16,2,8>(r, Mcry1);   // CRy(edge -> anc1)
  rotg<16,1,4>(r, Mcrz);    // CRz(neighbor -> anc2)
  rotg<16,1,8>(r, Mcry2);   // CRy(edge -> anc2)
  rotg<16,8,0>(r, S0e);     // strong0 rotations
  rotg<16,4,0>(r, S0n);
  rotg<16,2,0>(r, S0a);
  cnotg<16,4,8>(r);         // CNOT(edge -> neighbor)
  cnotg<16,2,4>(r);         // CNOT(neighbor -> anc1)
  cnotg<16,8,2>(r);         // CNOT(anc1 -> edge)
  rotg<16,2,0>(r, S1a);     // strong1 rotations
  rotg<16,4,0>(r, S1n);
  rotg<16,1,0>(r, S1x);
  cnotg<16,4,2>(r);         // CNOT(anc1 -> neighbor)
  cnotg<16,1,4>(r);         // CNOT(neighbor -> anc2)
  cnotg<16,2,1>(r);         // CNOT(anc2 -> anc1)
}

__device__ __forceinline__ void gatherg(const float2* lds, cplx* r, int base, int eb, int nb){
  #pragma unroll
  for (int j = 0; j < 16; ++j){
    int l = base | ((j >> 3) << eb) | (((j >> 2) & 1) << nb) | (j & 3);
    float2 v = lds[l]; r[j] = {v.x, v.y};
  }
}
__device__ __forceinline__ void scatterg(float2* lds, const cplx* r, int base, int eb, int nb){
  #pragma unroll
  for (int j = 0; j < 16; ++j){
    int l = base | ((j >> 3) << eb) | (((j >> 2) & 1) << nb) | (j & 3);
    lds[l] = make_float2(r[j].x, r[j].y);
  }
}

// ---------------- segment A: passes 0..3 over the 2^15-amp support ----------
// local bits: l0=g0 l1=g1 l2=g2 l3=g6 l4=g7 l5=g8 l6=g9 l7=g10 l8=g15 l9=g16 l10=g17 l11=g18
// block bits (blk 0..7): b0=g3 b1=g4 b2=g5
__global__ __launch_bounds__(256)
void segA(const float* __restrict__ inf, const float* __restrict__ inits,
          const float* __restrict__ s0p, const float* __restrict__ s1p,
          float2* __restrict__ buf)
{
  __shared__ float2 lds[4096];
  const int tid = threadIdx.x, blk = blockIdx.x;

  cplx Mcrx[4],Mcry1[4],Mcrz[4],Mcry2[4];
  mk_rx(inits[0],Mcrx); mk_ry(inits[1],Mcry1); mk_rz(inits[2],Mcrz); mk_ry(inits[3],Mcry2);
  cplx S0e[4],S0n[4],S0a[4],S1a[4],S1n[4],S1x[4];
  mk_strong(s0p+0,S0e); mk_strong(s0p+3,S0n); mk_strong(s0p+6,S0a);
  mk_strong(s1p+0,S1a); mk_strong(s1p+3,S1n); mk_strong(s1p+6,S1x);

  // pass 0: build initial product-state group directly (no LDS seed needed)
  {
    const int eb = 11, nb = 6;
    const int base = ins0(ins0(ins0(ins0(tid,0),1),nb),eb);
    cplx r[16];
    #pragma unroll
    for (int j = 0; j < 16; ++j) r[j] = {0.f, 0.f};
    if ((base & 0x700) == 0){            // g15,g16,g17 must be |0> initially
      // vert v <-> bit g(10-v); v1 (g9) is this pass's neighbor (in-register dim)
      cplx amp = {1.f, 0.f}, vn0 = {0,0}, vn1 = {0,0};
      #pragma unroll
      for (int v = 0; v < 9; ++v){
        float sy, cy, sz, cz;
        sincosf(0.5f * inf[16 + 2*v], &sy, &cy);
        sincosf(0.5f * inf[17 + 2*v], &sz, &cz);
        cplx q0 = {cy*cz, -cy*sz}, q1 = {sy*cz, sy*sz};
        int bit;
        if      (v == 0) bit = (base >> 7) & 1;   // g10
        else if (v == 1) { vn0 = q0; vn1 = q1; continue; }
        else if (v == 2) bit = (base >> 5) & 1;   // g8
        else if (v == 3) bit = (base >> 4) & 1;   // g7
        else if (v == 4) bit = (base >> 3) & 1;   // g6
        else if (v == 5) bit = (blk  >> 2) & 1;   // g5
        else if (v == 6) bit = (blk  >> 1) & 1;   // g4
        else if (v == 7) bit =  blk        & 1;   // g3
        else             bit = (base >> 2) & 1;   // g2
        amp = cmul(amp, bit ? q1 : q0);
      }
      r[0] = cmul(amp, vn0);
      r[4] = cmul(amp, vn1);
      cplx Ue[4]; mk_ryrz(inf[0], inf[1], Ue);
      edge_pass(r, Ue, Mcrx,Mcry1,Mcrz,Mcry2, S0e,S0n,S0a, S1a,S1n,S1x);
    }
    scatterg(lds, r, base, eb, nb);      // groups partition LDS: exclusive slots
  }

  for (int p = 1; p < 4; ++p){
    __syncthreads();
    const int eb = 11 - p, nb = 6 - p;
    const int base = ins0(ins0(ins0(ins0(tid,0),1),nb),eb);
    cplx r[16];
    gatherg(lds, r, base, eb, nb);
    cplx Ue[4]; mk_ryrz(inf[2*p], inf[2*p+1], Ue);
    edge_pass(r, Ue, Mcrx,Mcry1,Mcrz,Mcry2, S0e,S0n,S0a, S1a,S1n,S1x);
    scatterg(lds, r, base, eb, nb);
  }
  __syncthreads();

  // store to packed support buffer: s = [g18..g15 | g10..g0]
  for (int l = tid; l < 4096; l += 256){
    int s = ((l >> 8) << 11) | (((l >> 3) & 0x1F) << 6) | (blk << 3) | (l & 7);
    buf[s] = lds[l];
  }
}

// ---------------- segment B: passes 4..7 + update block + H + measure -------
// local bits: l0..l6 = g0..g6, l7=g10, l8=g11 l9=g12 l10=g13 l11=g14
// block bits (B 0..127): B0=g7 B1=g8 B2=g9 B3=g15 B4=g16 B5=g17 B6=g18
__global__ __launch_bounds__(256)
void segB(const float* __restrict__ inf, const float* __restrict__ inits,
          const float* __restrict__ s0p, const float* __restrict__ s1p,
          const float* __restrict__ up,
          const float2* __restrict__ buf, float* __restrict__ out)
{
  __shared__ float2 lds[4096];
  __shared__ float wsum[4];
  const int tid = threadIdx.x, B = blockIdx.x;

  cplx Mcrx[4],Mcry1[4],Mcrz[4],Mcry2[4];
  mk_rx(inits[0],Mcrx); mk_ry(inits[1],Mcry1); mk_rz(inits[2],Mcrz); mk_ry(inits[3],Mcry2);
  cplx S0e[4],S0n[4],S0a[4],S1a[4],S1n[4],S1x[4];
  mk_strong(s0p+0,S0e); mk_strong(s0p+3,S0n); mk_strong(s0p+6,S0a);
  mk_strong(s1p+0,S1a); mk_strong(s1p+3,S1n); mk_strong(s1p+6,S1x);

  // load support: g11..g14 == 0 -> local l in [0,256), one amp per thread
  {
    int s = ((B >> 3) << 11) | (((tid >> 7) & 1) << 10) | ((B & 7) << 7) | (tid & 0x7F);
    float2 v = buf[s];
    for (int l = tid; l < 4096; l += 256) lds[l] = make_float2(0.f, 0.f);
    lds[tid] = v;                      // same thread wrote lds[tid]=0 above: ordered
  }
  __syncthreads();

  for (int p = 4; p < 8; ++p){
    const int eb = 15 - p, nb = 9 - p;
    const int base = ins0(ins0(ins0(ins0(tid,0),1),nb),eb);
    cplx r[16];
    gatherg(lds, r, base, eb, nb);
    cplx Ue[4]; mk_ryrz(inf[2*p], inf[2*p+1], Ue);
    edge_pass(r, Ue, Mcrx,Mcry1,Mcrz,Mcry2, S0e,S0n,S0a, S1a,S1n,S1x);
    scatterg(lds, r, base, eb, nb);
    __syncthreads();
  }

  // finale: update strong block on {center=l7, anc1=l1, anc2=l0}, H on center,
  // measure Z on wire 10 = g8 = block bit B1 (uniform sign per block).
  cplx Uc[4],Ua1[4],Ua2[4];
  mk_strong(up+0,Uc); mk_strong(up+3,Ua1); mk_strong(up+6,Ua2);
  const float rh = 0.70710678118654752f;
  cplx HH[4] = {{rh,0.f},{rh,0.f},{rh,0.f},{-rh,0.f}};
  float acc = 0.f;
  #pragma unroll
  for (int u = 0; u < 2; ++u){
    const int idx  = tid + (u << 8);                    // 9 spectator bits
    const int base = ins0(ins0(ins0(idx,0),1),7);
    cplx r[8];                                          // j = c*4 + a1*2 + a2
    #pragma unroll
    for (int j = 0; j < 8; ++j){
      int l = base | ((j >> 2) << 7) | (j & 3);
      float2 v = lds[l]; r[j] = {v.x, v.y};
    }
    rotg<8,4,0>(r, Uc);
    rotg<8,2,0>(r, Ua1);
    rotg<8,1,0>(r, Ua2);
    cnotg<8,2,4>(r);                                    // CNOT(center -> anc1)
    cnotg<8,1,2>(r);                                    // CNOT(anc1 -> anc2)
    cnotg<8,4,1>(r);                                    // CNOT(anc2 -> center)
    rotg<8,4,0>(r, HH);                                 // H on center
    #pragma unroll
    for (int j = 0; j < 8; ++j) acc += r[j].x*r[j].x + r[j].y*r[j].y;
  }
  float sv = ((B >> 1) & 1) ? -acc : acc;
  for (int off = 32; off > 0; off >>= 1) sv += __shfl_down(sv, off);
  if ((tid & 63) == 0) wsum[tid >> 6] = sv;
  __syncthreads();
  if (tid == 0) atomicAdd(out, wsum[0] + wsum[1] + wsum[2] + wsum[3]);
}

extern "C" void kernel_launch(void* const* d_in, const int* in_sizes, int n_in,
                              void* d_out, int out_size, void* d_ws, size_t ws_size,
                              hipStream_t stream) {
  const float* inf   = (const float*)d_in[0];
  const float* inits = (const float*)d_in[1];
  const float* s0p   = (const float*)d_in[2];
  const float* s1p   = (const float*)d_in[3];
  const float* up    = (const float*)d_in[4];
  float* out  = (float*)d_out;
  float2* buf = (float2*)d_ws;                          // 2^15 float2 = 256 KB

  hipMemsetAsync(out, 0, sizeof(float), stream);
  segA<<<dim3(8),   dim3(256), 0, stream>>>(inf, inits, s0p, s1p, buf);
  segB<<<dim3(128), dim3(256), 0, stream>>>(inf, inits, s0p, s1p, up, buf, out);
}

// Round 4
// 115.388 us; speedup vs baseline: 2.8920x; 1.0025x over previous
//
#include <hip/hip_runtime.h>
#include <math.h>

// 19-qubit statevector sim in TWO kernels (global sync = kernel boundary).
// Wire w <-> global bit g(18-w).
// Passes 0-3 active bits: {g18..g15 (edges), g9..g6 (neighbors), g1 (anc1), g0 (anc2)}
// Passes 4-7 + finale:    {g14..g11, g5..g2, g10 (center), g1, g0}
// segA: 8 blocks x 256, 12 local bits {g0,g1,g2,g6..g10,g15..g18}, block bits {g3,g4,g5}.
//       Support has g11..g14 == 0 throughout (edges 4..7 untouched) -> 2^15 amps.
//       Also zeroes out[0] (replaces a separate memset dispatch).
// segB: 128 blocks x 256, 12 local bits {g0..g6,g10,g11..g14}, block bits {g7,g8,g9,g15..g18}.
// Interface: packed 15-bit support index s = [g18..g15 | g10..g0] in d_ws (256 KB).
// Within a pass each thread owns an exclusive 16-amp group (4 active bits) in
// registers; regroup via LDS with one __syncthreads between passes.
// Pass loops fully unrolled -> LDS addressing is constant-shift.

struct cplx { float x, y; };
__device__ __forceinline__ cplx cmul(cplx a, cplx b){ return {a.x*b.x - a.y*b.y, a.x*b.y + a.y*b.x}; }
__device__ __forceinline__ cplx cadd(cplx a, cplx b){ return {a.x+b.x, a.y+b.y}; }

__device__ __forceinline__ void mat2mul(const cplx* A, const cplx* B, cplx* C){
  C[0] = cadd(cmul(A[0],B[0]), cmul(A[1],B[2]));
  C[1] = cadd(cmul(A[0],B[1]), cmul(A[1],B[3]));
  C[2] = cadd(cmul(A[2],B[0]), cmul(A[3],B[2]));
  C[3] = cadd(cmul(A[2],B[1]), cmul(A[3],B[3]));
}
__device__ void mk_rz(float t, cplx* M){ float s,c; sincosf(0.5f*t,&s,&c); M[0]={c,-s};M[1]={0,0};M[2]={0,0};M[3]={c,s}; }
__device__ void mk_ry(float t, cplx* M){ float s,c; sincosf(0.5f*t,&s,&c); M[0]={c,0};M[1]={-s,0};M[2]={s,0};M[3]={c,0}; }
__device__ void mk_rx(float t, cplx* M){ float s,c; sincosf(0.5f*t,&s,&c); M[0]={c,0};M[1]={0,-s};M[2]={0,-s};M[3]={c,0}; }
// Rx(p2) Ry(p1) Rz(p0)
__device__ void mk_strong(const float* p, cplx* M){
  cplx Rz[4],Ry[4],Rx[4],T[4];
  mk_rz(p[0],Rz); mk_ry(p[1],Ry); mk_rx(p[2],Rx);
  mat2mul(Ry,Rz,T); mat2mul(Rx,T,M);
}
// Rz(tz) Ry(ty)
__device__ void mk_ryrz(float ty, float tz, cplx* M){
  cplx Rz[4],Ry[4]; mk_rz(tz,Rz); mk_ry(ty,Ry); mat2mul(Rz,Ry,M);
}

template<int N, int S, int C>
__device__ __forceinline__ void rotg(cplx* r, const cplx* M){
  #pragma unroll
  for (int j = 0; j < N; ++j){
    if (j & S) continue;
    if (C && !(j & C)) continue;
    cplx a = r[j], b = r[j | S];
    r[j]     = cadd(cmul(M[0], a), cmul(M[1], b));
    r[j | S] = cadd(cmul(M[2], a), cmul(M[3], b));
  }
}
template<int N, int S, int C>
__device__ __forceinline__ void cnotg(cplx* r){
  #pragma unroll
  for (int j = 0; j < N; ++j){
    if (j & S) continue;
    if (!(j & C)) continue;
    cplx t = r[j]; r[j] = r[j | S]; r[j | S] = t;
  }
}

__device__ __forceinline__ constexpr int ins0(int x, int b){
  return ((x >> b) << (b + 1)) | (x & ((1 << b) - 1));
}

// full edge-iteration gate sequence; j = (e<<3)|(n<<2)|(a1<<1)|a2
__device__ __forceinline__ void edge_pass(cplx* r, const cplx* Ue,
    const cplx* Mcrx, const cplx* Mcry1, const cplx* Mcrz, const cplx* Mcry2,
    const cplx* S0e, const cplx* S0n, const cplx* S0a,
    const cplx* S1a, const cplx* S1n, const cplx* S1x)
{
  rotg<16,8,0>(r, Ue);      // RzRy init on edge
  rotg<16,2,4>(r, Mcrx);    // CRx(neighbor -> anc1)
  rotg<16,2,8>(r, Mcry1);   // CRy(edge -> anc1)
  rotg<16,1,4>(r, Mcrz);    // CRz(neighbor -> anc2)
  rotg<16,1,8>(r, Mcry2);   // CRy(edge -> anc2)
  rotg<16,8,0>(r, S0e);     // strong0 rotations
  rotg<16,4,0>(r, S0n);
  rotg<16,2,0>(r, S0a);
  cnotg<16,4,8>(r);         // CNOT(edge -> neighbor)
  cnotg<16,2,4>(r);         // CNOT(neighbor -> anc1)
  cnotg<16,8,2>(r);         // CNOT(anc1 -> edge)
  rotg<16,2,0>(r, S1a);     // strong1 rotations
  rotg<16,4,0>(r, S1n);
  rotg<16,1,0>(r, S1x);
  cnotg<16,4,2>(r);         // CNOT(anc1 -> neighbor)
  cnotg<16,1,4>(r);         // CNOT(neighbor -> anc2)
  cnotg<16,2,1>(r);         // CNOT(anc2 -> anc1)
}

template<int EB, int NB>
__device__ __forceinline__ void gatherg(const float2* lds, cplx* r, int base){
  #pragma unroll
  for (int j = 0; j < 16; ++j){
    int l = base | ((j >> 3) << EB) | (((j >> 2) & 1) << NB) | (j & 3);
    float2 v = lds[l]; r[j] = {v.x, v.y};
  }
}
template<int EB, int NB>
__device__ __forceinline__ void scatterg(float2* lds, const cplx* r, int base){
  #pragma unroll
  for (int j = 0; j < 16; ++j){
    int l = base | ((j >> 3) << EB) | (((j >> 2) & 1) << NB) | (j & 3);
    lds[l] = make_float2(r[j].x, r[j].y);
  }
}

// ---------------- segment A: passes 0..3 over the 2^15-amp support ----------
// local bits: l0=g0 l1=g1 l2=g2 l3=g6 l4=g7 l5=g8 l6=g9 l7=g10 l8=g15 l9=g16 l10=g17 l11=g18
// block bits (blk 0..7): b0=g3 b1=g4 b2=g5
__global__ __launch_bounds__(256)
void segA(const float* __restrict__ inf, const float* __restrict__ inits,
          const float* __restrict__ s0p, const float* __restrict__ s1p,
          float2* __restrict__ buf, float* __restrict__ out)
{
  __shared__ float2 lds[4096];
  const int tid = threadIdx.x, blk = blockIdx.x;

  if (blk == 0 && tid == 0) out[0] = 0.f;   // replaces memset dispatch; segB runs after

  cplx Mcrx[4],Mcry1[4],Mcrz[4],Mcry2[4];
  mk_rx(inits[0],Mcrx); mk_ry(inits[1],Mcry1); mk_rz(inits[2],Mcrz); mk_ry(inits[3],Mcry2);
  cplx S0e[4],S0n[4],S0a[4],S1a[4],S1n[4],S1x[4];
  mk_strong(s0p+0,S0e); mk_strong(s0p+3,S0n); mk_strong(s0p+6,S0a);
  mk_strong(s1p+0,S1a); mk_strong(s1p+3,S1n); mk_strong(s1p+6,S1x);

  // pass 0: build initial product-state group directly (no LDS seed needed)
  {
    constexpr int eb = 11, nb = 6;
    const int base = ins0(ins0(ins0(ins0(tid,0),1),nb),eb);
    cplx r[16];
    #pragma unroll
    for (int j = 0; j < 16; ++j) r[j] = {0.f, 0.f};
    if ((base & 0x700) == 0){            // g15,g16,g17 must be |0> initially
      // vert v <-> bit g(10-v); v1 (g9) is this pass's neighbor (in-register dim)
      cplx amp = {1.f, 0.f}, vn0 = {0,0}, vn1 = {0,0};
      #pragma unroll
      for (int v = 0; v < 9; ++v){
        float sy, cy, sz, cz;
        sincosf(0.5f * inf[16 + 2*v], &sy, &cy);
        sincosf(0.5f * inf[17 + 2*v], &sz, &cz);
        cplx q0 = {cy*cz, -cy*sz}, q1 = {sy*cz, sy*sz};
        int bit;
        if      (v == 0) bit = (base >> 7) & 1;   // g10
        else if (v == 1) { vn0 = q0; vn1 = q1; continue; }
        else if (v == 2) bit = (base >> 5) & 1;   // g8
        else if (v == 3) bit = (base >> 4) & 1;   // g7
        else if (v == 4) bit = (base >> 3) & 1;   // g6
        else if (v == 5) bit = (blk  >> 2) & 1;   // g5
        else if (v == 6) bit = (blk  >> 1) & 1;   // g4
        else if (v == 7) bit =  blk        & 1;   // g3
        else             bit = (base >> 2) & 1;   // g2
        amp = cmul(amp, bit ? q1 : q0);
      }
      r[0] = cmul(amp, vn0);
      r[4] = cmul(amp, vn1);
      cplx Ue[4]; mk_ryrz(inf[0], inf[1], Ue);
      edge_pass(r, Ue, Mcrx,Mcry1,Mcrz,Mcry2, S0e,S0n,S0a, S1a,S1n,S1x);
    }
    scatterg<eb,nb>(lds, r, base);       // groups partition LDS: exclusive slots
  }

  #pragma unroll
  for (int p = 1; p < 4; ++p){
    __syncthreads();
    constexpr int pe[4] = {11,10,9,8}, pn[4] = {6,5,4,3};
    const int eb = pe[p], nb = pn[p];
    const int base = ins0(ins0(ins0(ins0(tid,0),1),nb),eb);
    cplx r[16];
    if (p == 1)      gatherg<10,5>(lds, r, base);
    else if (p == 2) gatherg<9,4>(lds, r, base);
    else             gatherg<8,3>(lds, r, base);
    cplx Ue[4]; mk_ryrz(inf[2*p], inf[2*p+1], Ue);
    edge_pass(r, Ue, Mcrx,Mcry1,Mcrz,Mcry2, S0e,S0n,S0a, S1a,S1n,S1x);
    if (p == 1)      scatterg<10,5>(lds, r, base);
    else if (p == 2) scatterg<9,4>(lds, r, base);
    else             scatterg<8,3>(lds, r, base);
  }
  __syncthreads();

  // store to packed support buffer: s = [g18..g15 | g10..g0]
  for (int l = tid; l < 4096; l += 256){
    int s = ((l >> 8) << 11) | (((l >> 3) & 0x1F) << 6) | (blk << 3) | (l & 7);
    buf[s] = lds[l];
  }
}

// ---------------- segment B: passes 4..7 + update block + H + measure -------
// local bits: l0..l6 = g0..g6, l7=g10, l8=g11 l9=g12 l10=g13 l11=g14
// block bits (B 0..127): B0=g7 B1=g8 B2=g9 B3=g15 B4=g16 B5=g17 B6=g18
__global__ __launch_bounds__(256)
void segB(const float* __restrict__ inf, const float* __restrict__ inits,
          const float* __restrict__ s0p, const float* __restrict__ s1p,
          const float* __restrict__ up,
          const float2* __restrict__ buf, float* __restrict__ out)
{
  __shared__ float2 lds[4096];
  __shared__ float wsum[4];
  const int tid = threadIdx.x, B = blockIdx.x;

  cplx Mcrx[4],Mcry1[4],Mcrz[4],Mcry2[4];
  mk_rx(inits[0],Mcrx); mk_ry(inits[1],Mcry1); mk_rz(inits[2],Mcrz); mk_ry(inits[3],Mcry2);
  cplx S0e[4],S0n[4],S0a[4],S1a[4],S1n[4],S1x[4];
  mk_strong(s0p+0,S0e); mk_strong(s0p+3,S0n); mk_strong(s0p+6,S0a);
  mk_strong(s1p+0,S1a); mk_strong(s1p+3,S1n); mk_strong(s1p+6,S1x);

  // load support: g11..g14 == 0 -> local l in [0,256), one amp per thread
  {
    int s = ((B >> 3) << 11) | (((tid >> 7) & 1) << 10) | ((B & 7) << 7) | (tid & 0x7F);
    float2 v = buf[s];
    for (int l = tid; l < 4096; l += 256) lds[l] = make_float2(0.f, 0.f);
    lds[tid] = v;                      // same thread wrote lds[tid]=0 above: ordered
  }
  __syncthreads();

  #pragma unroll
  for (int p = 4; p < 8; ++p){
    constexpr int pe[8] = {0,0,0,0,11,10,9,8}, pn[8] = {0,0,0,0,5,4,3,2};
    const int eb = pe[p], nb = pn[p];
    const int base = ins0(ins0(ins0(ins0(tid,0),1),nb),eb);
    cplx r[16];
    if (p == 4)      gatherg<11,5>(lds, r, base);
    else if (p == 5) gatherg<10,4>(lds, r, base);
    else if (p == 6) gatherg<9,3>(lds, r, base);
    else             gatherg<8,2>(lds, r, base);
    cplx Ue[4]; mk_ryrz(inf[2*p], inf[2*p+1], Ue);
    edge_pass(r, Ue, Mcrx,Mcry1,Mcrz,Mcry2, S0e,S0n,S0a, S1a,S1n,S1x);
    if (p == 4)      scatterg<11,5>(lds, r, base);
    else if (p == 5) scatterg<10,4>(lds, r, base);
    else if (p == 6) scatterg<9,3>(lds, r, base);
    else             scatterg<8,2>(lds, r, base);
    __syncthreads();
  }

  // finale: update strong block on {center=l7, anc1=l1, anc2=l0}, H on center,
  // measure Z on wire 10 = g8 = block bit B1 (uniform sign per block).
  cplx Uc[4],Ua1[4],Ua2[4];
  mk_strong(up+0,Uc); mk_strong(up+3,Ua1); mk_strong(up+6,Ua2);
  const float rh = 0.70710678118654752f;
  cplx HH[4] = {{rh,0.f},{rh,0.f},{rh,0.f},{-rh,0.f}};
  float acc = 0.f;
  #pragma unroll
  for (int u = 0; u < 2; ++u){
    const int idx  = tid + (u << 8);                    // 9 spectator bits
    const int base = ins0(ins0(ins0(idx,0),1),7);
    cplx r[8];                                          // j = c*4 + a1*2 + a2
    #pragma unroll
    for (int j = 0; j < 8; ++j){
      int l = base | ((j >> 2) << 7) | (j & 3);
      float2 v = lds[l]; r[j] = {v.x, v.y};
    }
    rotg<8,4,0>(r, Uc);
    rotg<8,2,0>(r, Ua1);
    rotg<8,1,0>(r, Ua2);
    cnotg<8,2,4>(r);                                    // CNOT(center -> anc1)
    cnotg<8,1,2>(r);                                    // CNOT(anc1 -> anc2)
    cnotg<8,4,1>(r);                                    // CNOT(anc2 -> center)
    rotg<8,4,0>(r, HH);                                 // H on center
    #pragma unroll
    for (int j = 0; j < 8; ++j) acc += r[j].x*r[j].x + r[j].y*r[j].y;
  }
  float sv = ((B >> 1) & 1) ? -acc : acc;
  for (int off = 32; off > 0; off >>= 1) sv += __shfl_down(sv, off);
  if ((tid & 63) == 0) wsum[tid >> 6] = sv;
  __syncthreads();
  if (tid == 0) atomicAdd(out, wsum[0] + wsum[1] + wsum[2] + wsum[3]);
}

extern "C" void kernel_launch(void* const* d_in, const int* in_sizes, int n_in,
                              void* d_out, int out_size, void* d_ws, size_t ws_size,
                              hipStream_t stream) {
  const float* inf   = (const float*)d_in[0];
  const float* inits = (const float*)d_in[1];
  const float* s0p   = (const float*)d_in[2];
  const float* s1p   = (const float*)d_in[3];
  const float* up    = (const float*)d_in[4];
  float* out  = (float*)d_out;
  float2* buf = (float2*)d_ws;                          // 2^15 float2 = 256 KB

  segA<<<dim3(8),   dim3(256), 0, stream>>>(inf, inits, s0p, s1p, buf, out);
  segB<<<dim3(128), dim3(256), 0, stream>>>(inf, inits, s0p, s1p, up, buf, out);
}

// Round 5
// 65.631 us; speedup vs baseline: 5.0845x; 1.7581x over previous
//
#include <hip/hip_runtime.h>
#include <math.h>

// Light-cone-reduced 19-qubit circuit.
// Measurement is <Z> on wire 10 (global bit g8). g8 is last touched in edge-pass 1
// (its neighbor role); every later gate (passes 2-7, update block, H on center)
// acts on other qubits, and Z_g8 commutes with them -> expectation frozen after
// pass 1. The entangled cluster at that point is {g18(edge0), g17(edge1),
// g9(vert1/neighbor0), g8(vert2/neighbor1), g1(anc1), g0(anc2)} = 6 qubits,
// 64 amplitudes. All other qubits are untouched norm-1 product factors.
// => ONE wavefront: lane l holds amplitude l (bits [b5..b0] = [g18,g17,g9,g8,g1,g0]),
// gates are shfl_xor butterflies. ~32 gates total, no LDS, no workspace.

struct cplx { float x, y; };
__device__ __forceinline__ cplx cmul(cplx a, cplx b){ return {a.x*b.x - a.y*b.y, a.x*b.y + a.y*b.x}; }
__device__ __forceinline__ cplx cadd(cplx a, cplx b){ return {a.x+b.x, a.y+b.y}; }

__device__ __forceinline__ void mat2mul(const cplx* A, const cplx* B, cplx* C){
  C[0] = cadd(cmul(A[0],B[0]), cmul(A[1],B[2]));
  C[1] = cadd(cmul(A[0],B[1]), cmul(A[1],B[3]));
  C[2] = cadd(cmul(A[2],B[0]), cmul(A[3],B[2]));
  C[3] = cadd(cmul(A[2],B[1]), cmul(A[3],B[3]));
}
__device__ void mk_rz(float t, cplx* M){ float s,c; sincosf(0.5f*t,&s,&c); M[0]={c,-s};M[1]={0,0};M[2]={0,0};M[3]={c,s}; }
__device__ void mk_ry(float t, cplx* M){ float s,c; sincosf(0.5f*t,&s,&c); M[0]={c,0};M[1]={-s,0};M[2]={s,0};M[3]={c,0}; }
__device__ void mk_rx(float t, cplx* M){ float s,c; sincosf(0.5f*t,&s,&c); M[0]={c,0};M[1]={0,-s};M[2]={0,-s};M[3]={c,0}; }
// Rx(p2) Ry(p1) Rz(p0)  (reference applies Rz, then Ry, then Rx)
__device__ void mk_strong(const float* p, cplx* M){
  cplx Rz[4],Ry[4],Rx[4],T[4];
  mk_rz(p[0],Rz); mk_ry(p[1],Ry); mk_rx(p[2],Rx);
  mat2mul(Ry,Rz,T); mat2mul(Rx,T,M);
}

// |q(bit)> component of Rz(tz)Ry(ty)|0>
__device__ __forceinline__ cplx spin(float ty, float tz, int bit){
  float sy,cy,sz,cz;
  sincosf(0.5f*ty,&sy,&cy);
  sincosf(0.5f*tz,&sz,&cz);
  return bit ? cplx{sy*cz, sy*sz} : cplx{cy*cz, -cy*sz};
}

__device__ __forceinline__ cplx shxor(cplx a, int m){
  return { __shfl_xor(a.x, m), __shfl_xor(a.y, m) };
}

// 1q gate M on lane-bit b; if c>=0, apply only where lane-bit c == 1
__device__ __forceinline__ void rot(cplx& amp, int lane, int b, const cplx* M, int c = -1){
  cplx p = shxor(amp, 1 << b);
  bool hi = (lane >> b) & 1;
  cplx lo_ = hi ? p : amp;
  cplx hi_ = hi ? amp : p;
  cplx na = hi ? cadd(cmul(M[2], lo_), cmul(M[3], hi_))
               : cadd(cmul(M[0], lo_), cmul(M[1], hi_));
  if (c >= 0 && !((lane >> c) & 1)) na = amp;
  amp = na;
}
// CNOT ctrl c -> target t
__device__ __forceinline__ void cnot(cplx& amp, int lane, int c, int t){
  cplx p = shxor(amp, 1 << t);
  if ((lane >> c) & 1) amp = p;
}

__global__ __launch_bounds__(64)
void qlightcone(const float* __restrict__ inf, const float* __restrict__ inits,
                const float* __restrict__ s0p, const float* __restrict__ s1p,
                float* __restrict__ out)
{
  const int lane = threadIdx.x;   // 0..63; bits [b5..b0]=[g18,g17,g9,g8,g1,g0]

  cplx Mcrx[4],Mcry1[4],Mcrz[4],Mcry2[4];
  mk_rx(inits[0],Mcrx); mk_ry(inits[1],Mcry1); mk_rz(inits[2],Mcrz); mk_ry(inits[3],Mcry2);
  cplx S0e[4],S0n[4],S0a[4],S1a[4],S1n[4],S1x[4];
  mk_strong(s0p+0,S0e); mk_strong(s0p+3,S0n); mk_strong(s0p+6,S0a);
  mk_strong(s1p+0,S1a); mk_strong(s1p+3,S1n); mk_strong(s1p+6,S1x);

  // initial product state: edge0=RzRy(inf[0],inf[1]) on b5, edge1=(inf[2],inf[3]) on b4,
  // vert1=(inf[18],inf[19]) on b3, vert2=(inf[20],inf[21]) on b2; anc b1=b0=|0>.
  cplx amp = {0.f, 0.f};
  if ((lane & 3) == 0){
    cplx a = cmul(spin(inf[0],  inf[1],  (lane >> 5) & 1),
                  spin(inf[2],  inf[3],  (lane >> 4) & 1));
    cplx b = cmul(spin(inf[18], inf[19], (lane >> 3) & 1),
                  spin(inf[20], inf[21], (lane >> 2) & 1));
    amp = cmul(a, b);
  }

  // edge-pass on (edge bit eb, neighbor bit nb, anc1=b1, anc2=b0)
  #pragma unroll
  for (int p = 0; p < 2; ++p){
    const int eb = 5 - p, nb = 3 - p;
    rot(amp, lane, 1, Mcrx,  nb);   // CRx(neighbor -> anc1)
    rot(amp, lane, 1, Mcry1, eb);   // CRy(edge -> anc1)
    rot(amp, lane, 0, Mcrz,  nb);   // CRz(neighbor -> anc2)
    rot(amp, lane, 0, Mcry2, eb);   // CRy(edge -> anc2)
    rot(amp, lane, eb, S0e);        // strong0 rotations: edge, neighbor, anc1
    rot(amp, lane, nb, S0n);
    rot(amp, lane, 1,  S0a);
    cnot(amp, lane, eb, nb);        // CNOT(edge -> neighbor)
    cnot(amp, lane, nb, 1);         // CNOT(neighbor -> anc1)
    cnot(amp, lane, 1,  eb);        // CNOT(anc1 -> edge)
    rot(amp, lane, 1,  S1a);        // strong1 rotations: anc1, neighbor, anc2
    rot(amp, lane, nb, S1n);
    rot(amp, lane, 0,  S1x);
    cnot(amp, lane, 1,  nb);        // CNOT(anc1 -> neighbor)
    cnot(amp, lane, nb, 0);         // CNOT(neighbor -> anc2)
    cnot(amp, lane, 0,  1);         // CNOT(anc2 -> anc1)
  }

  // <Z_g8> = sum |amp|^2 * (1 - 2*b2)
  float s = amp.x*amp.x + amp.y*amp.y;
  if ((lane >> 2) & 1) s = -s;
  for (int off = 32; off > 0; off >>= 1) s += __shfl_down(s, off);
  if (lane == 0) out[0] = s;
}

extern "C" void kernel_launch(void* const* d_in, const int* in_sizes, int n_in,
                              void* d_out, int out_size, void* d_ws, size_t ws_size,
                              hipStream_t stream) {
  const float* inf   = (const float*)d_in[0];
  const float* inits = (const float*)d_in[1];
  const float* s0p   = (const float*)d_in[2];
  const float* s1p   = (const float*)d_in[3];
  // d_in[4] (update_params) provably cannot affect <Z_g8>: unitary on other qubits.
  float* out = (float*)d_out;

  qlightcone<<<dim3(1), dim3(64), 0, stream>>>(inf, inits, s0p, s1p, out);
}

// Round 6
// 62.627 us; speedup vs baseline: 5.3284x; 1.0480x over previous
//
#include <hip/hip_runtime.h>
#include <math.h>

// Light-cone-reduced circuit (see round-5 derivation): <Z> on wire 10 (g8) is
// frozen after edge-pass 1; entangled cluster = {g18,g17,g9,g8,g1,g0} = 64 amps
// = ONE wavefront, lane bits [b5..b0]=[g18,g17,g9,g8,g1,g0].
// This round: minimize CODE size (kernel runs icache-cold every replay because
// the harness's 256MB ws-poison flushes L2). Gates run from a 32-entry op table
// in a scalar loop; the 10 rotation matrices are built by ONE generic RxRyRz
// path (lanes 0-9, one matrix each) into LDS; sincos = native __sinf/__cosf.

struct cplx { float x, y; };
__device__ __forceinline__ cplx cmul(cplx a, cplx b){ return {a.x*b.x - a.y*b.y, a.x*b.y + a.y*b.x}; }
__device__ __forceinline__ cplx cadd(cplx a, cplx b){ return {a.x+b.x, a.y+b.y}; }
__device__ __forceinline__ void mat2mul(const cplx* A, const cplx* B, cplx* C){
  C[0] = cadd(cmul(A[0],B[0]), cmul(A[1],B[2]));
  C[1] = cadd(cmul(A[0],B[1]), cmul(A[1],B[3]));
  C[2] = cadd(cmul(A[2],B[0]), cmul(A[3],B[2]));
  C[3] = cadd(cmul(A[2],B[1]), cmul(A[3],B[3]));
}

// op encoding: bit0 = kind (0=rot, 1=cnot); bits[4:1] = target bit;
// bits[8:5] = ctrl bit (15 = none); bits[12:9] = matrix index (rot only).
#define OPR(b,m,c) (unsigned short)(((m)<<9)|((c)<<5)|((b)<<1))
#define OPC(c,t)   (unsigned short)(((c)<<5)|((t)<<1)|1)
// matrices: 0 CRx-angle 1 CRy1 2 CRz 3 CRy2 4 S0e 5 S0n 6 S0a 7 S1a 8 S1n 9 S1x
#define PASS(eb,nb) \
  OPR(1,0,nb), OPR(1,1,eb), OPR(0,2,nb), OPR(0,3,eb), \
  OPR(eb,4,15), OPR(nb,5,15), OPR(1,6,15), \
  OPC(eb,nb), OPC(nb,1), OPC(1,eb), \
  OPR(1,7,15), OPR(nb,8,15), OPR(0,9,15), \
  OPC(1,nb), OPC(nb,0), OPC(0,1)

__device__ const unsigned short OPS[32] = { PASS(5,3), PASS(4,2) };

// component of Rz(tz)Ry(ty)|0>
__device__ __forceinline__ cplx spin(float ty, float tz, int bit){
  float sy = __sinf(0.5f*ty), cy = __cosf(0.5f*ty);
  float sz = __sinf(0.5f*tz), cz = __cosf(0.5f*tz);
  return bit ? cplx{sy*cz, sy*sz} : cplx{cy*cz, -cy*sz};
}

__global__ __launch_bounds__(64)
void qlightcone(const float* __restrict__ inf, const float* __restrict__ inits,
                const float* __restrict__ s0p, const float* __restrict__ s1p,
                float* __restrict__ out)
{
  __shared__ float2 Mlds[10][4];
  const int lane = threadIdx.x;

  // ---- build the 10 gate matrices, one per lane, single generic code path.
  // M = Rx(tx) * Ry(ty) * Rz(tz)  (reference applies Rz, Ry, Rx in that order).
  {
    const int ml = (lane < 10) ? lane : 4;
    float tx = 0.f, ty = 0.f, tz = 0.f;
    if (ml < 4){
      float a = inits[ml];
      tx = (ml == 0) ? a : 0.f;
      ty = (ml == 1 || ml == 3) ? a : 0.f;
      tz = (ml == 2) ? a : 0.f;
    } else {
      const float* pp = (ml < 7) ? s0p + 3*(ml - 4) : s1p + 3*(ml - 7);
      tz = pp[0]; ty = pp[1]; tx = pp[2];
    }
    float sx = __sinf(0.5f*tx), cx = __cosf(0.5f*tx);
    float sy = __sinf(0.5f*ty), cy = __cosf(0.5f*ty);
    float sz = __sinf(0.5f*tz), cz = __cosf(0.5f*tz);
    cplx Rz[4] = {{cz,-sz},{0,0},{0,0},{cz,sz}};
    cplx Ry[4] = {{cy,0},{-sy,0},{sy,0},{cy,0}};
    cplx Rx[4] = {{cx,0},{0,-sx},{0,-sx},{cx,0}};
    cplx T[4], M[4];
    mat2mul(Ry, Rz, T); mat2mul(Rx, T, M);
    if (lane < 10){
      #pragma unroll
      for (int j = 0; j < 4; ++j) Mlds[lane][j] = make_float2(M[j].x, M[j].y);
    }
  }

  // ---- initial product state: edge0(b5), edge1(b4), vert1(b3), vert2(b2); anc=|0>
  cplx amp = cmul(cmul(spin(inf[0],  inf[1],  (lane >> 5) & 1),
                       spin(inf[2],  inf[3],  (lane >> 4) & 1)),
                  cmul(spin(inf[18], inf[19], (lane >> 3) & 1),
                       spin(inf[20], inf[21], (lane >> 2) & 1)));
  if (lane & 3) amp = {0.f, 0.f};
  __syncthreads();

  // ---- gate loop (scalar-uniform decode; per-lane work is shfl + few VALU)
  for (int i = 0; i < 32; ++i){
    const int op   = OPS[i];
    const int b    = (op >> 1) & 15;
    const int c    = (op >> 5) & 15;
    const cplx p   = { __shfl_xor(amp.x, 1 << b), __shfl_xor(amp.y, 1 << b) };
    const bool cok = (c == 15) || ((lane >> c) & 1);
    if (op & 1){                       // CNOT: swap pair where ctrl set
      if (cok) amp = p;
    } else {                           // controlled/plain 2x2 rotation
      const int m = (op >> 9) & 15;
      float2 f0 = Mlds[m][0], f1 = Mlds[m][1], f2 = Mlds[m][2], f3 = Mlds[m][3];
      const bool hi = (lane >> b) & 1;
      cplx lo_ = hi ? p : amp, hi_ = hi ? amp : p;
      cplx A = hi ? cplx{f2.x,f2.y} : cplx{f0.x,f0.y};
      cplx B = hi ? cplx{f3.x,f3.y} : cplx{f1.x,f1.y};
      cplx na = cadd(cmul(A, lo_), cmul(B, hi_));
      if (cok) amp = na;
    }
  }

  // ---- <Z_g8> = sum |amp|^2 * (1 - 2*b2)
  float s = amp.x*amp.x + amp.y*amp.y;
  if ((lane >> 2) & 1) s = -s;
  #pragma unroll
  for (int off = 32; off > 0; off >>= 1) s += __shfl_down(s, off);
  if (lane == 0) out[0] = s;
}

extern "C" void kernel_launch(void* const* d_in, const int* in_sizes, int n_in,
                              void* d_out, int out_size, void* d_ws, size_t ws_size,
                              hipStream_t stream) {
  const float* inf   = (const float*)d_in[0];
  const float* inits = (const float*)d_in[1];
  const float* s0p   = (const float*)d_in[2];
  const float* s1p   = (const float*)d_in[3];
  // d_in[4] (update_params) provably cannot affect <Z_g8>: unitary outside the light cone.
  float* out = (float*)d_out;

  qlightcone<<<dim3(1), dim3(64), 0, stream>>>(inf, inits, s0p, s1p, out);
}